// Round 1
// baseline (124.718 us; speedup 1.0000x reference)
//
#include <hip/hip_runtime.h>

#define B_ 32
#define S_ 8192
#define D_ 256
#define NSPLIT 4

// ws layout (floats):
//   wh      [B_*D_]        @ 0
//   ctx     [B_*D_]        @ 8192
//   attn    [B_*S_]        @ 16384
//   partial [NSPLIT*B_*S_] @ 278528

// K1: wh[b,d] = sum_e W[e,d] * h[b,e]
__global__ __launch_bounds__(256) void k_wh(const float* __restrict__ W,
                                            const float* __restrict__ h,
                                            float* __restrict__ wh) {
  const int b = blockIdx.x;
  const int d = threadIdx.x;
  __shared__ float hs[D_];
  hs[d] = h[b * D_ + d];
  __syncthreads();
  float acc = 0.f;
#pragma unroll 8
  for (int e = 0; e < D_; ++e) acc = fmaf(W[e * D_ + d], hs[e], acc);
  wh[b * D_ + d] = acc;
}

// K2: partial[z,b,s] = sum_{d in z-chunk} cv[b,d,s] * wh[b,d]
__global__ __launch_bounds__(256) void k_scores(const float* __restrict__ cv,
                                                const float* __restrict__ wh,
                                                float* __restrict__ partial) {
  const int b = blockIdx.y;
  const int z = blockIdx.z;
  const int s4 = (blockIdx.x * 256 + threadIdx.x) * 4;
  __shared__ float whs[64];
  if (threadIdx.x < 64) whs[threadIdx.x] = wh[b * D_ + z * 64 + threadIdx.x];
  __syncthreads();
  const float* base = cv + (size_t)b * D_ * S_ + (size_t)(z * 64) * S_ + s4;
  float ax = 0.f, ay = 0.f, az = 0.f, aw = 0.f;
#pragma unroll 8
  for (int d = 0; d < 64; ++d) {
    const float4 v = *reinterpret_cast<const float4*>(base + (size_t)d * S_);
    const float w = whs[d];
    ax = fmaf(v.x, w, ax); ay = fmaf(v.y, w, ay);
    az = fmaf(v.z, w, az); aw = fmaf(v.w, w, aw);
  }
  float4 r; r.x = ax; r.y = ay; r.z = az; r.w = aw;
  *reinterpret_cast<float4*>(partial + ((size_t)z * B_ + b) * S_ + s4) = r;
}

// K3: masked softmax over S per batch row; writes attn[b,s]
__global__ __launch_bounds__(1024) void k_softmax(const float* __restrict__ partial,
                                                  const int* __restrict__ mask,
                                                  float* __restrict__ attn) {
  const int b = blockIdx.x;
  const int t = threadIdx.x;           // 1024 threads = 16 waves
  const int wave = t >> 6, lane = t & 63;
  __shared__ float red[16];
  const float NEG_INF = -__builtin_inff();

  float sc[8];
  float m = NEG_INF;
#pragma unroll
  for (int j = 0; j < 8; ++j) {
    const int s = j * 1024 + t;
    float v = 0.f;
#pragma unroll
    for (int z = 0; z < NSPLIT; ++z) v += partial[((size_t)z * B_ + b) * S_ + s];
    if (mask[b * S_ + s] != 0) v = NEG_INF;
    sc[j] = v;
    m = fmaxf(m, v);
  }
  // block max
  for (int off = 32; off > 0; off >>= 1) m = fmaxf(m, __shfl_down(m, off, 64));
  if (lane == 0) red[wave] = m;
  __syncthreads();
  float bm = red[0];
#pragma unroll
  for (int w = 1; w < 16; ++w) bm = fmaxf(bm, red[w]);
  __syncthreads();

  float e[8];
  float sum = 0.f;
#pragma unroll
  for (int j = 0; j < 8; ++j) {
    e[j] = __expf(sc[j] - bm);   // exp(-inf) == 0 for masked entries
    sum += e[j];
  }
  for (int off = 32; off > 0; off >>= 1) sum += __shfl_down(sum, off, 64);
  if (lane == 0) red[wave] = sum;
  __syncthreads();
  float bs = 0.f;
#pragma unroll
  for (int w = 0; w < 16; ++w) bs += red[w];
  const float inv = 1.0f / bs;
#pragma unroll
  for (int j = 0; j < 8; ++j) {
    const int s = j * 1024 + t;
    attn[b * S_ + s] = e[j] * inv;
  }
}

// K4: ctx[b,d] = sum_s cv[b,d,s] * attn[b,s]
__global__ __launch_bounds__(256) void k_ctx(const float* __restrict__ cv,
                                             const float* __restrict__ attn,
                                             float* __restrict__ ctx) {
  const int d = blockIdx.x;
  const int b = blockIdx.y;
  const int t = threadIdx.x;           // 256 threads = 4 waves
  const float* base = cv + ((size_t)b * D_ + d) * S_;
  const float* ab = attn + (size_t)b * S_;
  float acc = 0.f;
#pragma unroll
  for (int j = 0; j < 8; ++j) {
    const int s4 = (j * 256 + t) * 4;
    const float4 v = *reinterpret_cast<const float4*>(base + s4);
    const float4 a = *reinterpret_cast<const float4*>(ab + s4);
    acc += v.x * a.x + v.y * a.y + v.z * a.z + v.w * a.w;
  }
  for (int off = 32; off > 0; off >>= 1) acc += __shfl_down(acc, off, 64);
  __shared__ float red[4];
  const int wave = t >> 6, lane = t & 63;
  if (lane == 0) red[wave] = acc;
  __syncthreads();
  if (t == 0) ctx[b * D_ + d] = red[0] + red[1] + red[2] + red[3];
}

// K5: broadcast ctx -> out[0:seqlen,B,D], attn -> out[..., seqlen,B,S]
__global__ __launch_bounds__(256) void k_bcast(const float4* __restrict__ ctx4,
                                               const float4* __restrict__ attn4,
                                               float4* __restrict__ out4,
                                               long ctxQuads, long total4) {
  const long stride = (long)gridDim.x * blockDim.x;
  for (long idx = (long)blockIdx.x * blockDim.x + threadIdx.x; idx < total4;
       idx += stride) {
    float4 v;
    if (idx < ctxQuads) {
      v = ctx4[idx & (long)(B_ * D_ / 4 - 1)];       // repeats every B*D floats
    } else {
      v = attn4[(idx - ctxQuads) & (long)(B_ * S_ / 4 - 1)];  // every B*S floats
    }
    out4[idx] = v;
  }
}

extern "C" void kernel_launch(void* const* d_in, const int* in_sizes, int n_in,
                              void* d_out, int out_size, void* d_ws, size_t ws_size,
                              hipStream_t stream) {
  // inputs: 0=seqlen(1), 1=hidden(B*D), 2=contextvects(B*D*S), 3=W(D*D),
  //         4=b(D) [softmax-invariant, unused], 5=padding_mask(B*S)
  const float* hidden = (const float*)d_in[1];
  const float* cv = (const float*)d_in[2];
  const float* W = (const float*)d_in[3];
  const int* mask = (const int*)d_in[5];

  float* ws = (float*)d_ws;
  float* wh = ws;
  float* ctx = ws + 8192;
  float* attn = ws + 16384;
  float* partial = ws + 278528;

  k_wh<<<B_, D_, 0, stream>>>(W, hidden, wh);
  k_scores<<<dim3(S_ / 1024, B_, NSPLIT), 256, 0, stream>>>(cv, wh, partial);
  k_softmax<<<B_, 1024, 0, stream>>>(partial, mask, attn);
  k_ctx<<<dim3(D_, B_), 256, 0, stream>>>(cv, attn, ctx);

  const long seqlen = (long)out_size / (B_ * D_ + B_ * S_);
  const long ctxQuads = seqlen * B_ * D_ / 4;
  const long total4 = (long)out_size / 4;
  k_bcast<<<2048, 256, 0, stream>>>((const float4*)ctx, (const float4*)attn,
                                    (float4*)d_out, ctxQuads, total4);
}

// Round 2
// 100.294 us; speedup vs baseline: 1.2435x; 1.2435x over previous
//
#include <hip/hip_runtime.h>
#include <math.h>

#define B_ 32
#define S_ 8192
#define D_ 256
#define TS 64          // s-tile width
#define NT (S_ / TS)   // 128 tiles per batch row

// ws layout (floats):
//   wh    [B_*D_]        @ 0
//   ctx   [B_*D_]        @ 8192
//   sc    [B_*S_]        @ 16384
//   attn  [B_*S_]        @ 278528
//   ml    [B_*NT*2]      @ 540672
//   opart [B_*NT*D_]     @ 548864   (ends 1597440 floats = 6.4 MB)

// K1: wh[b,d] = sum_e W[e,d] * h[b,e]
__global__ __launch_bounds__(256) void k_wh(const float* __restrict__ W,
                                            const float* __restrict__ h,
                                            float* __restrict__ wh) {
  const int b = blockIdx.x;
  const int d = threadIdx.x;
  __shared__ float hs[D_];
  hs[d] = h[b * D_ + d];
  __syncthreads();
  float acc = 0.f;
#pragma unroll 8
  for (int e = 0; e < D_; ++e) acc = fmaf(W[e * D_ + d], hs[e], acc);
  wh[b * D_ + d] = acc;
}

// K2 (fused): per (s-tile, b): stage D x TS tile in LDS, compute scores,
// per-tile softmax (m_i, l_i), and partial context o_i[d] — cv read ONCE.
__global__ __launch_bounds__(256, 2) void k_fused(const float* __restrict__ cv,
                                                  const float* __restrict__ wh,
                                                  const int* __restrict__ mask,
                                                  float* __restrict__ sc,
                                                  float* __restrict__ ml,
                                                  float* __restrict__ opart) {
  __shared__ float tile[D_][TS];     // 64 KiB, stride 64 (aligned b128 writes)
  __shared__ float whs[D_];
  __shared__ float ps[TS];
  __shared__ float scred[4][TS];
  const int b = blockIdx.y;
  const int t0 = blockIdx.x;         // tile index
  const int t = threadIdx.x;
  const int s0 = t0 * TS;

  whs[t] = wh[b * D_ + t];

  // phase 1: global -> LDS, coalesced float4, aligned b128 LDS writes
  const float* src = cv + (size_t)b * D_ * S_ + s0;
#pragma unroll
  for (int it = 0; it < 16; ++it) {
    const int qi = t + it * 256;
    const int d = qi >> 4, q = qi & 15;
    const float4 v = *reinterpret_cast<const float4*>(src + (size_t)d * S_ + 4 * q);
    *reinterpret_cast<float4*>(&tile[d][4 * q]) = v;
  }
  __syncthreads();

  // phase 2: score[s] = sum_d tile[d][s] * whs[d]; 4 waves split d
  const int s = t & 63, dg = t >> 6;
  float p = 0.f;
#pragma unroll 8
  for (int dd = 0; dd < 64; ++dd) {
    const int d = dg * 64 + dd;
    p = fmaf(tile[d][s], whs[d], p);   // lanes hit distinct banks (2-way, free)
  }
  scred[dg][s] = p;
  __syncthreads();

  if (t < 64) {
    float v = scred[0][s] + scred[1][s] + scred[2][s] + scred[3][s];
    if (mask[b * S_ + s0 + s] != 0) v = -INFINITY;
    sc[(size_t)b * S_ + s0 + s] = v;
    float m = v;
    for (int off = 32; off > 0; off >>= 1) m = fmaxf(m, __shfl_xor(m, off, 64));
    m = fmaxf(m, -1e30f);              // guard fully-masked tile: exp(-inf-(-1e30))=0
    const float e = __expf(v - m);     // masked -> exp(-inf)=0
    ps[s] = e;
    float l = e;
    for (int off = 32; off > 0; off >>= 1) l += __shfl_xor(l, off, 64);
    if (s == 0) {
      ml[((size_t)b * NT + t0) * 2] = m;
      ml[((size_t)b * NT + t0) * 2 + 1] = l;
    }
  }
  __syncthreads();

  // phase 3: o[d] = sum_s ps[s] * tile[d][s], lane-rotated to dodge bank conflicts
  const int lane = t & 63;
  float acc = 0.f;
#pragma unroll 8
  for (int j = 0; j < 64; ++j) {
    const int ss = (lane + j) & 63;
    acc = fmaf(tile[t][ss], ps[ss], acc);
  }
  opart[((size_t)b * NT + t0) * D_ + t] = acc;
}

// K3: combine per-tile partials -> ctx[b,d]; also write normalized attn row
__global__ __launch_bounds__(256) void k_combine(const float* __restrict__ ml,
                                                 const float* __restrict__ opart,
                                                 const float* __restrict__ sc,
                                                 float* __restrict__ ctx,
                                                 float* __restrict__ attn) {
  const int b = blockIdx.x, t = threadIdx.x;
  __shared__ float em[NT];
  __shared__ float red[4];
  const float m = (t < NT) ? ml[((size_t)b * NT + t) * 2] : -INFINITY;
  const float l = (t < NT) ? ml[((size_t)b * NT + t) * 2 + 1] : 0.f;

  float mm = m;
  for (int off = 32; off > 0; off >>= 1) mm = fmaxf(mm, __shfl_xor(mm, off, 64));
  if ((t & 63) == 0) red[t >> 6] = mm;
  __syncthreads();
  const float M = fmaxf(fmaxf(red[0], red[1]), fmaxf(red[2], red[3]));
  __syncthreads();

  const float e = (t < NT) ? __expf(m - M) : 0.f;
  if (t < NT) em[t] = e;
  float ll = l * e;
  for (int off = 32; off > 0; off >>= 1) ll += __shfl_xor(ll, off, 64);
  if ((t & 63) == 0) red[t >> 6] = ll;
  __syncthreads();
  const float L = red[0] + red[1] + red[2] + red[3];
  const float invL = 1.0f / L;

  float acc = 0.f;
  for (int i = 0; i < NT; ++i)
    acc = fmaf(opart[((size_t)b * NT + i) * D_ + t], em[i], acc);
  ctx[b * D_ + t] = acc * invL;

#pragma unroll 4
  for (int it = 0; it < S_ / 256; ++it) {
    const int si = it * 256 + t;
    attn[(size_t)b * S_ + si] = __expf(sc[(size_t)b * S_ + si] - M) * invL;
  }
}

// K4: broadcast ctx -> out[0:seqlen,B,D], attn -> out[..., seqlen,B,S]
__global__ __launch_bounds__(256) void k_bcast(const float4* __restrict__ ctx4,
                                               const float4* __restrict__ attn4,
                                               float4* __restrict__ out4,
                                               long ctxQuads, long total4) {
  const long stride = (long)gridDim.x * blockDim.x;
  for (long idx = (long)blockIdx.x * blockDim.x + threadIdx.x; idx < total4;
       idx += stride) {
    float4 v;
    if (idx < ctxQuads) {
      v = ctx4[idx & (long)(B_ * D_ / 4 - 1)];
    } else {
      v = attn4[(idx - ctxQuads) & (long)(B_ * S_ / 4 - 1)];
    }
    out4[idx] = v;
  }
}

extern "C" void kernel_launch(void* const* d_in, const int* in_sizes, int n_in,
                              void* d_out, int out_size, void* d_ws, size_t ws_size,
                              hipStream_t stream) {
  // inputs: 0=seqlen(1), 1=hidden(B*D), 2=contextvects(B*D*S), 3=W(D*D),
  //         4=b(D) [softmax-invariant, unused], 5=padding_mask(B*S)
  const float* hidden = (const float*)d_in[1];
  const float* cv = (const float*)d_in[2];
  const float* W = (const float*)d_in[3];
  const int* mask = (const int*)d_in[5];

  float* ws = (float*)d_ws;
  float* wh = ws;
  float* ctx = ws + 8192;
  float* sc = ws + 16384;
  float* attn = ws + 278528;
  float* ml = ws + 540672;
  float* opart = ws + 548864;

  k_wh<<<B_, D_, 0, stream>>>(W, hidden, wh);
  k_fused<<<dim3(NT, B_), 256, 0, stream>>>(cv, wh, mask, sc, ml, opart);
  k_combine<<<B_, 256, 0, stream>>>(ml, opart, sc, ctx, attn);

  const long seqlen = (long)out_size / (B_ * D_ + B_ * S_);
  const long ctxQuads = seqlen * B_ * D_ / 4;
  const long total4 = (long)out_size / 4;
  k_bcast<<<2048, 256, 0, stream>>>((const float4*)ctx, (const float4*)attn,
                                    (float4*)d_out, ctxQuads, total4);
}